// Round 1
// baseline (119.175 us; speedup 1.0000x reference)
//
#include <hip/hip_runtime.h>
#include <hip/hip_fp16.h>

#define N_CB 15

// Monotonic float<->uint mapping: order-preserving for atomicMin/atomicMax.
__device__ __forceinline__ unsigned f2ord(float f) {
    unsigned u = __float_as_uint(f);
    return (u & 0x80000000u) ? ~u : (u | 0x80000000u);
}
__device__ __forceinline__ float ord2f(unsigned u) {
    return (u & 0x80000000u) ? __uint_as_float(u & 0x7fffffffu)
                             : __uint_as_float(~u);
}

// ws layout (32-bit words):
//   [0] ordered-uint running min
//   [1] ordered-uint running max
//   [2..16] codebook as f32 (15 entries)
__global__ void q4_init_kernel(const void* __restrict__ cb_raw, unsigned* __restrict__ ws) {
    int t = threadIdx.x;
    if (t == 62) ws[0] = 0xFFFFFFFFu;  // ordered +inf -> min slot
    if (t == 63) ws[1] = 0u;           // ordered -inf -> max slot
    if (t < N_CB) {
        // Sniff codebook dtype: codebook[0] is exactly -1.0. If the buffer is
        // f32, the first word is 0xBF800000 (== -1.0f). If it is raw fp16, the
        // first word is 0xXXXXBC00 (tiny denormal-ish float, != -1.0f).
        const float* cf = (const float*)cb_raw;
        float v;
        if (cf[0] == -1.0f) {
            v = cf[t];
        } else {
            const __half* ch = (const __half*)cb_raw;
            v = __half2float(ch[t]);
        }
        ((float*)ws)[2 + t] = v;
    }
}

__global__ void q4_minmax_kernel(const float4* __restrict__ x4, int n4,
                                 const float* __restrict__ x, int n,
                                 unsigned* __restrict__ ws) {
    float mn = 3.402823466e38f, mx = -3.402823466e38f;
    int stride = gridDim.x * blockDim.x;
    for (int i = blockIdx.x * blockDim.x + threadIdx.x; i < n4; i += stride) {
        float4 v = x4[i];
        mn = fminf(mn, fminf(fminf(v.x, v.y), fminf(v.z, v.w)));
        mx = fmaxf(mx, fmaxf(fmaxf(v.x, v.y), fmaxf(v.z, v.w)));
    }
    // scalar tail (n not divisible by 4) — handled by block 0 threads
    if (blockIdx.x == 0) {
        for (int i = n4 * 4 + threadIdx.x; i < n; i += blockDim.x) {
            float v = x[i];
            mn = fminf(mn, v);
            mx = fmaxf(mx, v);
        }
    }
    // wave-64 butterfly reduce
    #pragma unroll
    for (int off = 32; off; off >>= 1) {
        mn = fminf(mn, __shfl_down(mn, off));
        mx = fmaxf(mx, __shfl_down(mx, off));
    }
    __shared__ float smn[4], smx[4];
    int wave = threadIdx.x >> 6, lane = threadIdx.x & 63;
    if (lane == 0) { smn[wave] = mn; smx[wave] = mx; }
    __syncthreads();
    if (threadIdx.x == 0) {
        mn = fminf(fminf(smn[0], smn[1]), fminf(smn[2], smn[3]));
        mx = fmaxf(fmaxf(smx[0], smx[1]), fmaxf(smx[2], smx[3]));
        atomicMin(&ws[0], f2ord(mn));
        atomicMax(&ws[1], f2ord(mx));
    }
}

__device__ __forceinline__ float q4_lookup(float xv, float mn, float range,
                                           const float* cb) {
    // EXACT f32 mirror of the reference:
    //   t = (x - mn) / (mx - mn) * 2.0f + (-1.0f)
    // (mul by 2 is exact, so fma-contraction cannot change the result;
    //  the division is kept — no reciprocal — to match np rounding).
    float t = (xv - mn) / range * 2.0f - 1.0f;
    float best = fabsf(t - cb[0]);
    float val  = cb[0];
    #pragma unroll
    for (int j = 1; j < N_CB; j++) {
        float d = fabsf(t - cb[j]);
        if (d < best) { best = d; val = cb[j]; }  // strict <: first-index tie-break == jnp.argmin
    }
    return val;
}

__global__ void q4_transform_kernel(const float4* __restrict__ x4, float4* __restrict__ out4,
                                    int n4,
                                    const float* __restrict__ x, float* __restrict__ out, int n,
                                    const unsigned* __restrict__ ws) {
    float mn = ord2f(ws[0]);
    float mx = ord2f(ws[1]);
    float range = mx - mn;
    float cb[N_CB];
    const float* cbw = (const float*)(ws + 2);
    #pragma unroll
    for (int j = 0; j < N_CB; j++) cb[j] = cbw[j];

    int i = blockIdx.x * blockDim.x + threadIdx.x;
    if (i < n4) {
        float4 v = x4[i];
        float4 o;
        o.x = q4_lookup(v.x, mn, range, cb);
        o.y = q4_lookup(v.y, mn, range, cb);
        o.z = q4_lookup(v.z, mn, range, cb);
        o.w = q4_lookup(v.w, mn, range, cb);
        out4[i] = o;
    }
    // scalar tail
    if (blockIdx.x == 0) {
        for (int k = n4 * 4 + threadIdx.x; k < n; k += blockDim.x) {
            out[k] = q4_lookup(x[k], mn, range, cb);
        }
    }
}

extern "C" void kernel_launch(void* const* d_in, const int* in_sizes, int n_in,
                              void* d_out, int out_size, void* d_ws, size_t ws_size,
                              hipStream_t stream) {
    const float* x = (const float*)d_in[0];
    const void* cb = d_in[1];
    float* out = (float*)d_out;   // fp16 reference output -> f32 buffer per harness
    int n = in_sizes[0];          // 2048*4096 = 8388608
    int n4 = n >> 2;
    unsigned* ws = (unsigned*)d_ws;

    q4_init_kernel<<<1, 64, 0, stream>>>(cb, ws);

    // 1024 blocks x 256 threads: each thread reduces ~8 float4s, 2 atomics/block.
    q4_minmax_kernel<<<1024, 256, 0, stream>>>((const float4*)x, n4, x, n, ws);

    int blocks = (n4 + 255) / 256;
    q4_transform_kernel<<<blocks, 256, 0, stream>>>((const float4*)x, (float4*)out, n4,
                                                    x, out, n, ws);
}

// Round 2
// 97.325 us; speedup vs baseline: 1.2245x; 1.2245x over previous
//
#include <hip/hip_runtime.h>
#include <hip/hip_fp16.h>
#include <float.h>

#define N_CB 15
#define A_BLOCKS 512
#define A_THREADS 256
#define B_THREADS 256

// ws float layout:
//   [0    ..  511]  per-block mins  (kernel A)
//   [512  .. 1023]  per-block maxs  (kernel A)
//   [1024 .. 1038]  codebook as f32 (kernel A, block 0)
// No init kernel needed: every slot we read is written earlier this call.

__global__ __launch_bounds__(A_THREADS) void q4_partials_kernel(
        const float4* __restrict__ x4, int n4,
        const float* __restrict__ x, int n,
        float* __restrict__ ws, const void* __restrict__ cb_raw) {
    // Codebook dtype sniff + convert (block 0 only). codebook[0] is exactly
    // -1.0: f32 layout iff first word == 0xBF800000; raw fp16 otherwise.
    if (blockIdx.x == 0 && threadIdx.x < N_CB) {
        const float* cf = (const float*)cb_raw;
        float v;
        if (cf[0] == -1.0f) v = cf[threadIdx.x];
        else                v = __half2float(((const __half*)cb_raw)[threadIdx.x]);
        ws[1024 + threadIdx.x] = v;
    }

    float mn = FLT_MAX, mx = -FLT_MAX;
    int tid = blockIdx.x * A_THREADS + threadIdx.x;
    int stride = gridDim.x * A_THREADS;
    for (int i = tid; i < n4; i += stride) {
        float4 v = x4[i];
        mn = fminf(mn, fminf(fminf(v.x, v.y), fminf(v.z, v.w)));
        mx = fmaxf(mx, fmaxf(fmaxf(v.x, v.y), fmaxf(v.z, v.w)));
    }
    // scalar tail (n % 4 != 0), block 0 only — no-op for this shape
    if (blockIdx.x == 0) {
        for (int i = n4 * 4 + threadIdx.x; i < n; i += A_THREADS) {
            float v = x[i];
            mn = fminf(mn, v);
            mx = fmaxf(mx, v);
        }
    }
    // wave-64 reduce
    #pragma unroll
    for (int off = 32; off; off >>= 1) {
        mn = fminf(mn, __shfl_down(mn, off));
        mx = fmaxf(mx, __shfl_down(mx, off));
    }
    __shared__ float smn[4], smx[4];
    int wave = threadIdx.x >> 6, lane = threadIdx.x & 63;
    if (lane == 0) { smn[wave] = mn; smx[wave] = mx; }
    __syncthreads();
    if (threadIdx.x == 0) {
        ws[blockIdx.x]       = fminf(fminf(smn[0], smn[1]), fminf(smn[2], smn[3]));
        ws[512 + blockIdx.x] = fmaxf(fmaxf(smx[0], smx[1]), fmaxf(smx[2], smx[3]));
    }
}

__device__ __forceinline__ float q4_lookup(float xv, float mn, float range,
                                           const float* cb) {
    // EXACT f32 mirror of the reference: t = (x-mn)/(mx-mn) * 2.0f + (-1.0f).
    // Real division (no reciprocal); *2.0f is exponent-exact so fma
    // contraction cannot change the rounded result.
    float t = (xv - mn) / range * 2.0f - 1.0f;
    float best = fabsf(t - cb[0]);
    float val  = cb[0];
    #pragma unroll
    for (int j = 1; j < N_CB; j++) {
        float d = fabsf(t - cb[j]);
        if (d < best) { best = d; val = cb[j]; }  // strict <: first-index tie-break == jnp.argmin
    }
    return val;
}

__global__ __launch_bounds__(B_THREADS) void q4_transform_kernel(
        const float4* __restrict__ x4, float4* __restrict__ out4, int n4,
        const float* __restrict__ x, float* __restrict__ out, int n,
        const float* __restrict__ ws) {
    // Issue the global x loads FIRST so the partial-reduce latency hides
    // under them (2 float4 / thread, coalesced: thread t -> base, base+256).
    int base = blockIdx.x * (B_THREADS * 2) + threadIdx.x;
    bool h0 = base < n4, h1 = (base + B_THREADS) < n4;
    float4 v0, v1;
    if (h0) v0 = x4[base];
    if (h1) v1 = x4[base + B_THREADS];

    // Reduce the 512 per-block partials (all L2-hot).
    float mn = fminf(ws[threadIdx.x],       ws[threadIdx.x + 256]);
    float mx = fmaxf(ws[512 + threadIdx.x], ws[768 + threadIdx.x]);
    #pragma unroll
    for (int off = 32; off; off >>= 1) {
        mn = fminf(mn, __shfl_down(mn, off));
        mx = fmaxf(mx, __shfl_down(mx, off));
    }
    __shared__ float sred[8];
    __shared__ float sfin[2];
    int wave = threadIdx.x >> 6, lane = threadIdx.x & 63;
    if (lane == 0) { sred[wave] = mn; sred[4 + wave] = mx; }
    __syncthreads();
    if (threadIdx.x == 0) {
        sfin[0] = fminf(fminf(sred[0], sred[1]), fminf(sred[2], sred[3]));
        sfin[1] = fmaxf(fmaxf(sred[4], sred[5]), fmaxf(sred[6], sred[7]));
    }
    float cb[N_CB];
    #pragma unroll
    for (int j = 0; j < N_CB; j++) cb[j] = ws[1024 + j];
    __syncthreads();
    float fmn = sfin[0];
    float range = sfin[1] - fmn;

    if (h0) {
        float4 o;
        o.x = q4_lookup(v0.x, fmn, range, cb);
        o.y = q4_lookup(v0.y, fmn, range, cb);
        o.z = q4_lookup(v0.z, fmn, range, cb);
        o.w = q4_lookup(v0.w, fmn, range, cb);
        out4[base] = o;
    }
    if (h1) {
        float4 o;
        o.x = q4_lookup(v1.x, fmn, range, cb);
        o.y = q4_lookup(v1.y, fmn, range, cb);
        o.z = q4_lookup(v1.z, fmn, range, cb);
        o.w = q4_lookup(v1.w, fmn, range, cb);
        out4[base + B_THREADS] = o;
    }
    // scalar tail, block 0 only — no-op for this shape
    if (blockIdx.x == 0) {
        for (int k = n4 * 4 + threadIdx.x; k < n; k += B_THREADS) {
            out[k] = q4_lookup(x[k], fmn, range, cb);
        }
    }
}

extern "C" void kernel_launch(void* const* d_in, const int* in_sizes, int n_in,
                              void* d_out, int out_size, void* d_ws, size_t ws_size,
                              hipStream_t stream) {
    const float* x = (const float*)d_in[0];
    const void* cb = d_in[1];
    float* out = (float*)d_out;   // fp16 reference output -> f32 buffer per harness
    int n = in_sizes[0];          // 2048*4096
    int n4 = n >> 2;
    float* ws = (float*)d_ws;

    q4_partials_kernel<<<A_BLOCKS, A_THREADS, 0, stream>>>(
        (const float4*)x, n4, x, n, ws, cb);

    int bblocks = (n4 + B_THREADS * 2 - 1) / (B_THREADS * 2);
    q4_transform_kernel<<<bblocks, B_THREADS, 0, stream>>>(
        (const float4*)x, (float4*)out, n4, x, out, n, ws);
}